// Round 8
// baseline (433.752 us; speedup 1.0000x reference)
//
#include <hip/hip_runtime.h>
#include <math.h>

#define DIM   1024
#define NE    64
#define BM    64
#define BK    16
#define NT    64                 // 1024/16 k-tiles
#define A_BYTES 4096             // 64 tok x 4 float4-slots (linear)
#define B_BYTES 20480            // 320 col x 4 float4-slots (kq source-swizzled)
#define TILE_BYTES (A_BYTES + B_BYTES)   // 24576; x2 = 48 KB

// global -> LDS direct copy, 16B/lane; LDS dest = wave-uniform base + lane*16.
__device__ __forceinline__ void gload16(const void* gptr, void* lptr) {
  __builtin_amdgcn_global_load_lds(
      (const __attribute__((address_space(1))) unsigned int*)(unsigned long long)gptr,
      (__attribute__((address_space(3))) unsigned int*)(unsigned int)(unsigned long long)lptr,
      16, 0, 0);
}

__global__ __launch_bounds__(256)
void ur_fused(const float* __restrict__ hs,    // [M,1024]
              const float* __restrict__ Wr,    // [64,1024]
              const float* __restrict__ br,    // [64]
              const float* __restrict__ Wu1,   // [256,1024]
              const float* __restrict__ bu1,   // [256]
              const float* __restrict__ Wu2,   // [256]
              const float* __restrict__ bu2,   // [1]
              float* __restrict__ out,         // w[4M] | idx[4M] | k[M]
              int M) {
  __shared__ __align__(16) char smem[2 * TILE_BYTES];

  const int tid = threadIdx.x;
  const int m0 = blockIdx.x * BM;
  const int r = tid >> 5;        // 0..7  -> tokens 8r..8r+7
  const int c = tid & 31;        // 0..31 -> cols c+32n, n=0..9

  // ---- staging (slot = 256l + tid, 16B each, linear LDS dest) ----
  // A (1 issue): slot = 4*ta + kqs; ta = tid>>2, kqs = tid&3; global linear.
  // B (5 issues): col = 64l + (tid>>2), kqs = tid&3; source k-chunk
  //   kq_g = kqs ^ ((col>>1)&3) = (tid&3) ^ ((tid>>3)&3)  (l-invariant, m173).
  const int t4 = tid >> 2, k4 = tid & 3;
  const int kqg = k4 ^ ((tid >> 3) & 3);
  const char* pA  = (const char*)hs  + (size_t)(m0 + t4) * 4096 + (k4 << 4);
  const char* pB0 = (const char*)Wr  + (size_t)t4 * 4096 + (kqg << 4);
  const char* pB1 = (const char*)Wu1 + (size_t)t4 * 4096 + (kqg << 4);
  const unsigned wb = (unsigned)(tid & ~63) * 16u;   // wave-uniform lane-0 part

  float acc[8][10];
#pragma unroll
  for (int j = 0; j < 8; ++j)
#pragma unroll
    for (int n = 0; n < 10; ++n) acc[j][n] = 0.f;

  const int csw = (tid >> 1) & 3;    // == (c>>1)&3, B read swizzle key

  auto stage = [&](char* base) {
    gload16(pA, base + wb);                                   // A slots
    gload16(pB0, base + A_BYTES + 0 * 4096 + wb);             // cols 0..63 (Wr)
    gload16(pB1, base + A_BYTES + 1 * 4096 + wb);             // cols 64..127
    gload16(pB1 + 262144, base + A_BYTES + 2 * 4096 + wb);    // cols 128..191
    gload16(pB1 + 524288, base + A_BYTES + 3 * 4096 + wb);    // cols 192..255
    gload16(pB1 + 786432, base + A_BYTES + 4 * 4096 + wb);    // cols 256..319
    pA += 64; pB0 += 64; pB1 += 64;                           // next BK chunk
  };

  auto compute = [&](const char* base) {
    const char* Ab = base + r * 512;                 // 8 tokens x 64 B
    const char* Bb = base + A_BYTES + c * 64;
#pragma unroll
    for (int kq = 0; kq < 4; ++kq) {
      float4 av[8];
#pragma unroll
      for (int j = 0; j < 8; ++j)                    // 2-addr broadcast reads
        av[j] = *reinterpret_cast<const float4*>(Ab + j * 64 + (kq << 4));
      const int qb = (kq ^ csw) << 4;
#pragma unroll
      for (int n = 0; n < 10; ++n) {
        const float4 bv = *reinterpret_cast<const float4*>(Bb + n * 2048 + qb);
#pragma unroll
        for (int j = 0; j < 8; ++j) {
          acc[j][n] = fmaf(av[j].x, bv.x, acc[j][n]);
          acc[j][n] = fmaf(av[j].y, bv.y, acc[j][n]);
          acc[j][n] = fmaf(av[j].z, bv.z, acc[j][n]);
          acc[j][n] = fmaf(av[j].w, bv.w, acc[j][n]);
        }
      }
    }
  };

  // ---- double-buffered main loop: ONE stage + ONE compute per iteration,
  //      counted vmcnt(6) so next tile's loads span the barrier (T3/T4) ----
  unsigned off = 0;
  stage(smem);
#pragma unroll 1
  for (int t = 0; t < NT - 1; ++t) {
    stage(smem + (off ^ TILE_BYTES));                       // tile t+1 in flight
    asm volatile("s_waitcnt vmcnt(6)" ::: "memory");        // tile t resident
    __builtin_amdgcn_s_barrier();
    compute(smem + off);
    asm volatile("" ::: "memory");
    __builtin_amdgcn_s_barrier();                           // readers done
    off ^= TILE_BYTES;
  }
  asm volatile("s_waitcnt vmcnt(0)" ::: "memory");
  __builtin_amdgcn_s_barrier();
  compute(smem + off);                                      // last tile
  __syncthreads();     // tile buffers dead; overlay epilogue arrays

  // ---- epilogue: bias, GELU, uncertainty dot (overlaid LDS) ----
  float* Lg = reinterpret_cast<float*>(smem);                 // [64][65]
  float* Xp = reinterpret_cast<float*>(smem + 16640);         // [32][65]
  float* Xs = reinterpret_cast<float*>(smem + 16640 + 8320);  // [64]

  float xp[8] = {0, 0, 0, 0, 0, 0, 0, 0};
#pragma unroll
  for (int n = 0; n < 10; ++n) {
    int col = c + 32 * n;
    if (n < 2) {                   // router cols 0..63
      float bias = br[col];
#pragma unroll
      for (int j = 0; j < 8; ++j) Lg[(8 * r + j) * 65 + col] = acc[j][n] + bias;
    } else {                       // u1 cols 64..319
      int qd = col - NE;
      float w2 = Wu2[qd];
      float b1 = bu1[qd];
#pragma unroll
      for (int j = 0; j < 8; ++j) {
        float h = acc[j][n] + b1;
        float g = 0.5f * h * (1.f + erff(h * 0.70710678118654752440f));
        xp[j] = fmaf(g, w2, xp[j]);
      }
    }
  }
#pragma unroll
  for (int j = 0; j < 8; ++j) Xp[c * 65 + 8 * r + j] = xp[j];
  __syncthreads();

  if (tid < BM) {
    float x = bu2[0];
#pragma unroll
    for (int cc = 0; cc < 32; ++cc) x += Xp[cc * 65 + tid];
    Xs[tid] = x;
  }
  __syncthreads();

  // ---- per-token top-4 + masked softmax: one wave per token ----
  const int wave = tid >> 6;
  const int lane = tid & 63;
  const size_t Moff_i = 4 * (size_t)M;
  const size_t Moff_k = 8 * (size_t)M;

  for (int t = wave; t < BM; t += 4) {
    float cur = Lg[t * 65 + lane];
    float topv[4];
    int topi[4];
#pragma unroll
    for (int s = 0; s < 4; ++s) {
      float mv = cur;
      int mi = lane;
#pragma unroll
      for (int off2 = 32; off2 >= 1; off2 >>= 1) {
        float ov = __shfl_xor(mv, off2, 64);
        int oi = __shfl_xor(mi, off2, 64);
        if (ov > mv || (ov == mv && oi < mi)) { mv = ov; mi = oi; }
      }
      topv[s] = mv;
      topi[s] = mi;
      if (lane == mi) cur = -INFINITY;   // stable: lowest index wins ties
    }
    if (lane == 0) {
      const int token = m0 + t;
      float x = Xs[t];
      float u = 1.f / (1.f + expf(-x));
      float kf = fmaf(3.f, u, 1.f);
      int kv = (int)rintf(kf);           // round-half-even == jnp.round
      kv = kv < 1 ? 1 : (kv > 4 ? 4 : kv);

      float w[4];
#pragma unroll
      for (int s = 0; s < 4; ++s) w[s] = (s < kv) ? topv[s] : 0.f;
      float mx = fmaxf(fmaxf(w[0], w[1]), fmaxf(w[2], w[3]));
      float e[4], sum = 0.f;
#pragma unroll
      for (int s = 0; s < 4; ++s) { e[s] = expf(w[s] - mx); sum += e[s]; }
      float inv = 1.f / sum;
#pragma unroll
      for (int s = 0; s < 4; ++s) {
        out[(size_t)token * 4 + s] = e[s] * inv;
        out[Moff_i + (size_t)token * 4 + s] = (s < kv) ? (float)topi[s] : -1.0f;
      }
      out[Moff_k + token] = (float)kv;
    }
  }
}

extern "C" void kernel_launch(void* const* d_in, const int* in_sizes, int n_in,
                              void* d_out, int out_size, void* d_ws, size_t ws_size,
                              hipStream_t stream) {
  (void)n_in; (void)d_ws; (void)ws_size; (void)out_size;
  const float* hs  = (const float*)d_in[0];
  const float* Wr  = (const float*)d_in[1];
  const float* br  = (const float*)d_in[2];
  const float* Wu1 = (const float*)d_in[3];
  const float* bu1 = (const float*)d_in[4];
  const float* Wu2 = (const float*)d_in[5];
  const float* bu2 = (const float*)d_in[6];
  float* out = (float*)d_out;

  const int M = in_sizes[0] / DIM;  // 32768
  dim3 grid(M / BM);                // 512 blocks, 2-3/CU resident (48 KB LDS)
  dim3 block(256);
  hipLaunchKernelGGL(ur_fused, grid, block, 0, stream,
                     hs, Wr, br, Wu1, bu1, Wu2, bu2, out, M);
}

// Round 11
// 321.462 us; speedup vs baseline: 1.3493x; 1.3493x over previous
//
#include <hip/hip_runtime.h>
#include <hip/hip_bf16.h>
#include <math.h>

#define DIM 1024
#define NE  64
#define BM  64
#define NT  32                    // 1024/32 k-tiles
#define A_BYTES 8192              // 64 tok x 8 fp32-chunks x 16B
#define B_BYTES 40960             // 320 col x 8 fp32-chunks x 16B
#define LDS_BYTES (A_BYTES + B_BYTES)   // 49152

typedef __attribute__((ext_vector_type(8))) short short8;
typedef __attribute__((ext_vector_type(4))) float f32x4;

__device__ __forceinline__ void gload16(const void* gptr, void* lptr) {
  __builtin_amdgcn_global_load_lds(
      (const __attribute__((address_space(1))) unsigned int*)(unsigned long long)gptr,
      (__attribute__((address_space(3))) unsigned int*)(unsigned int)(unsigned long long)lptr,
      16, 0, 0);
}

// 3-term bf16 split (RNE): f = h + m + l + O(2^-27 |f|); f-h and r1-m exact (Sterbenz)
__device__ __forceinline__ void bsplit(float f, unsigned short& h,
                                       unsigned short& m, unsigned short& l) {
  __hip_bfloat16 bh = __float2bfloat16(f);
  float r1 = f - __bfloat162float(bh);
  __hip_bfloat16 bm = __float2bfloat16(r1);
  __hip_bfloat16 bl = __float2bfloat16(r1 - __bfloat162float(bm));
  h = *reinterpret_cast<unsigned short*>(&bh);
  m = *reinterpret_cast<unsigned short*>(&bm);
  l = *reinterpret_cast<unsigned short*>(&bl);
}

__global__ __launch_bounds__(256)
void ur_hyb(const float* __restrict__ hs,    // [M,1024]
            const float* __restrict__ Wr,    // [64,1024]
            const float* __restrict__ br,    // [64]
            const float* __restrict__ Wu1,   // [256,1024]
            const float* __restrict__ bu1,   // [256]
            const float* __restrict__ Wu2,   // [256]
            const float* __restrict__ bu2,   // [1]
            float* __restrict__ out,         // w[4M] | idx[4M] | k[M]
            int M) {
  __shared__ __align__(16) char smem[LDS_BYTES];

  const int tid = threadIdx.x;
  const int m0 = blockIdx.x * BM;
  // router (fp32 VALU) coords: thread (r, c5) -> tokens 8r..8r+7, cols c5, c5+32
  const int r = tid >> 5, c5 = tid & 31;
  // mfma (u1) coords: wave w -> u1 cols 64w..64w+63
  const int w = tid >> 6, l = tid & 63, g = l >> 4, c = l & 15;

  // ---- staging (R5/R10 pattern): LDS[row][q] = src[row][q ^ (row&7)],
  //      linear LDS dest (gload_lds), XOR applied on the GLOBAL source side ----
  const int t8 = tid >> 3, k8 = tid & 7;
  const int kx = k8 ^ (t8 & 7);
  const char* pA  = (const char*)hs  + (size_t)(m0 + t8) * 4096 + (kx << 4);
  const char* pB0 = (const char*)Wr  + (size_t)t8 * 4096 + (kx << 4);
  const char* pB1 = (const char*)Wu1 + (size_t)t8 * 4096 + (kx << 4);
  const unsigned wb = (unsigned)(tid & ~63) * 16u;

  // router read bases
  const char* Ar = smem + r * 1024;                 // token 8r (128 B/row)
  const unsigned rb0 = (unsigned)(A_BYTES + c5 * 128);
  const unsigned rsw = (unsigned)(c5 & 7);
  // mfma fragment read offsets (global chunks 2g, 2g+1 at slot q^(row&7), row&7==c&7)
  const unsigned axk0 = (unsigned)(((2 * g) ^ (c & 7)) << 4);
  const unsigned axk1 = (unsigned)(((2 * g + 1) ^ (c & 7)) << 4);
  const unsigned abase = (unsigned)(c * 128);
  const unsigned bub = (unsigned)(A_BYTES + 8192 + w * 8192 + c * 128);  // u1 rows 64+64w+16n+c

  float ar[8][2];
#pragma unroll
  for (int j = 0; j < 8; ++j) { ar[j][0] = 0.f; ar[j][1] = 0.f; }
  f32x4 am_[4][4];
#pragma unroll
  for (int s = 0; s < 4; ++s)
#pragma unroll
    for (int n = 0; n < 4; ++n) am_[s][n] = (f32x4){0.f, 0.f, 0.f, 0.f};

#pragma unroll 1
  for (int t = 0; t < NT; ++t) {
    __syncthreads();   // previous tile's readers done
    gload16(pA, smem + wb);                                  // A rows 0..31
    gload16(pA + 131072, smem + 4096 + wb);                  // A rows 32..63
    pA += 128;
    gload16(pB0, smem + A_BYTES + wb);                       // B rows 0..31 (Wr)
    gload16(pB0 + 131072, smem + A_BYTES + 4096 + wb);       // B rows 32..63
#pragma unroll
    for (int li = 2; li < 10; ++li)                          // B rows 64..319 (Wu1)
      gload16(pB1 + (size_t)(li - 2) * 131072, smem + A_BYTES + li * 4096 + wb);
    pB0 += 128; pB1 += 128;
    __syncthreads();   // tile resident

    // ---- phase 1: router logits, scalar fp32, k-sequential (R5-proven) ----
#pragma unroll
    for (int kq = 0; kq < 8; ++kq) {
      f32x4 av[8];
#pragma unroll
      for (int j = 0; j < 8; ++j)
        av[j] = *reinterpret_cast<const f32x4*>(Ar + j * 128 + ((kq ^ j) << 4));
#pragma unroll
      for (int n = 0; n < 2; ++n) {
        const f32x4 bv = *reinterpret_cast<const f32x4*>(
            smem + rb0 + n * 4096 + ((kq ^ rsw) << 4));
#pragma unroll
        for (int j = 0; j < 8; ++j) {
          ar[j][n] = fmaf(av[j][0], bv[0], ar[j][n]);
          ar[j][n] = fmaf(av[j][1], bv[1], ar[j][n]);
          ar[j][n] = fmaf(av[j][2], bv[2], ar[j][n]);
          ar[j][n] = fmaf(av[j][3], bv[3], ar[j][n]);
        }
      }
    }

    // ---- phase 2: A fragments -> 3-term bf16 split ----
    short8 Ah[4], Am[4], Al[4];
#pragma unroll
    for (int s = 0; s < 4; ++s) {
      const f32x4 v0 = *reinterpret_cast<const f32x4*>(smem + abase + s * 2048 + axk0);
      const f32x4 v1 = *reinterpret_cast<const f32x4*>(smem + abase + s * 2048 + axk1);
#pragma unroll
      for (int e = 0; e < 4; ++e) {
        unsigned short h, m, lo;
        bsplit(v0[e], h, m, lo);
        Ah[s][e] = (short)h; Am[s][e] = (short)m; Al[s][e] = (short)lo;
        bsplit(v1[e], h, m, lo);
        Ah[s][4 + e] = (short)h; Am[s][4 + e] = (short)m; Al[s][4 + e] = (short)lo;
      }
    }

    // ---- phase 3: u1 head via MFMA, 6 products (err ~2^-26 rel) ----
#pragma unroll
    for (int n = 0; n < 4; ++n) {
      const char* bp = smem + bub + n * 2048;
      const f32x4 u0 = *reinterpret_cast<const f32x4*>(bp + axk0);
      const f32x4 u1v = *reinterpret_cast<const f32x4*>(bp + axk1);
      short8 Bh, Bm, Bl;
#pragma unroll
      for (int e = 0; e < 4; ++e) {
        unsigned short h, m, lo;
        bsplit(u0[e], h, m, lo);
        Bh[e] = (short)h; Bm[e] = (short)m; Bl[e] = (short)lo;
        bsplit(u1v[e], h, m, lo);
        Bh[4 + e] = (short)h; Bm[4 + e] = (short)m; Bl[4 + e] = (short)lo;
      }
#pragma unroll
      for (int s = 0; s < 4; ++s) {
        am_[s][n] = __builtin_amdgcn_mfma_f32_16x16x32_bf16(Al[s], Bh, am_[s][n], 0, 0, 0);
        am_[s][n] = __builtin_amdgcn_mfma_f32_16x16x32_bf16(Ah[s], Bl, am_[s][n], 0, 0, 0);
        am_[s][n] = __builtin_amdgcn_mfma_f32_16x16x32_bf16(Am[s], Bm, am_[s][n], 0, 0, 0);
        am_[s][n] = __builtin_amdgcn_mfma_f32_16x16x32_bf16(Am[s], Bh, am_[s][n], 0, 0, 0);
        am_[s][n] = __builtin_amdgcn_mfma_f32_16x16x32_bf16(Ah[s], Bm, am_[s][n], 0, 0, 0);
        am_[s][n] = __builtin_amdgcn_mfma_f32_16x16x32_bf16(Ah[s], Bh, am_[s][n], 0, 0, 0);
      }
    }
  }
  __syncthreads();     // tile buffer dead; overlay epilogue arrays

  float* Lg = reinterpret_cast<float*>(smem);                 // [64][65]
  float* Xp = reinterpret_cast<float*>(smem + 16640);         // [64][65]
  float* Xs = reinterpret_cast<float*>(smem + 33280);         // [64]

  // router logits -> Lg (fp32 path)
#pragma unroll
  for (int n = 0; n < 2; ++n) {
    const int col = c5 + 32 * n;
    const float bias = br[col];
#pragma unroll
    for (int j = 0; j < 8; ++j) Lg[(8 * r + j) * 65 + col] = ar[j][n] + bias;
  }

  // u1 -> GELU -> dot W_u2. C/D [m89]: am_[s][n][reg] = h1[16s+4g+reg][64w+16n+c]
  float xp[4][4];
#pragma unroll
  for (int s = 0; s < 4; ++s)
#pragma unroll
    for (int reg = 0; reg < 4; ++reg) xp[s][reg] = 0.f;
#pragma unroll
  for (int n = 0; n < 4; ++n) {
    const int qd = 64 * w + 16 * n + c;        // u1-local col 0..255
    const float w2 = Wu2[qd];
    const float b1 = bu1[qd];
#pragma unroll
    for (int s = 0; s < 4; ++s)
#pragma unroll
      for (int reg = 0; reg < 4; ++reg) {
        float h = am_[s][n][reg] + b1;
        float ge = 0.5f * h * (1.f + erff(h * 0.70710678118654752440f));
        xp[s][reg] = fmaf(ge, w2, xp[s][reg]);
      }
  }
#pragma unroll
  for (int s = 0; s < 4; ++s)
#pragma unroll
    for (int reg = 0; reg < 4; ++reg)
      Xp[(w * 16 + c) * 65 + 16 * s + 4 * g + reg] = xp[s][reg];
  __syncthreads();

  if (tid < BM) {
    float x = bu2[0];
#pragma unroll
    for (int cc = 0; cc < 64; ++cc) x += Xp[cc * 65 + tid];
    Xs[tid] = x;
  }
  __syncthreads();

  // ---- per-token top-4 + masked softmax: one wave per token (R5-proven) ----
  const size_t Moff_i = 4 * (size_t)M;
  const size_t Moff_k = 8 * (size_t)M;

  for (int t = w; t < BM; t += 4) {
    float cur = Lg[t * 65 + l];
    float topv[4];
    int topi[4];
#pragma unroll
    for (int s = 0; s < 4; ++s) {
      float mv = cur;
      int mi = l;
#pragma unroll
      for (int off = 32; off >= 1; off >>= 1) {
        float ov = __shfl_xor(mv, off, 64);
        int oi = __shfl_xor(mi, off, 64);
        if (ov > mv || (ov == mv && oi < mi)) { mv = ov; mi = oi; }
      }
      topv[s] = mv;
      topi[s] = mi;
      if (l == mi) cur = -INFINITY;        // stable: lowest index wins ties
    }
    if (l == 0) {
      const int token = m0 + t;
      float x = Xs[t];
      float u = 1.f / (1.f + expf(-x));
      float kf = fmaf(3.f, u, 1.f);
      int kv = (int)rintf(kf);             // round-half-even == jnp.round
      kv = kv < 1 ? 1 : (kv > 4 ? 4 : kv);

      float wv[4];
#pragma unroll
      for (int s = 0; s < 4; ++s) wv[s] = (s < kv) ? topv[s] : 0.f;
      float mx = fmaxf(fmaxf(wv[0], wv[1]), fmaxf(wv[2], wv[3]));
      float e[4], sum = 0.f;
#pragma unroll
      for (int s = 0; s < 4; ++s) { e[s] = expf(wv[s] - mx); sum += e[s]; }
      float inv = 1.f / sum;
#pragma unroll
      for (int s = 0; s < 4; ++s) {
        out[(size_t)token * 4 + s] = e[s] * inv;
        out[Moff_i + (size_t)token * 4 + s] = (s < kv) ? (float)topi[s] : -1.0f;
      }
      out[Moff_k + token] = (float)kv;
    }
  }
}

extern "C" void kernel_launch(void* const* d_in, const int* in_sizes, int n_in,
                              void* d_out, int out_size, void* d_ws, size_t ws_size,
                              hipStream_t stream) {
  (void)n_in; (void)d_ws; (void)ws_size; (void)out_size;
  const float* hs  = (const float*)d_in[0];
  const float* Wr  = (const float*)d_in[1];
  const float* br  = (const float*)d_in[2];
  const float* Wu1 = (const float*)d_in[3];
  const float* bu1 = (const float*)d_in[4];
  const float* Wu2 = (const float*)d_in[5];
  const float* bu2 = (const float*)d_in[6];
  float* out = (float*)d_out;

  const int M = in_sizes[0] / DIM;  // 32768
  dim3 grid(M / BM);                // 512 blocks, 48 KB LDS
  dim3 block(256);
  hipLaunchKernelGGL(ur_hyb, grid, block, 0, stream,
                     hs, Wr, br, Wu1, bu1, Wu2, bu2, out, M);
}

// Round 12
// 294.543 us; speedup vs baseline: 1.4726x; 1.0914x over previous
//
#include <hip/hip_runtime.h>
#include <hip/hip_bf16.h>
#include <math.h>

#define DIM 1024
#define NE  64
#define BM  64
#define NT  32                    // 1024/32 k-tiles
// LDS: [2][A 8KB | Br 8KB] dbuf + Bu1 32KB single = 64KB
#define HALF_BYTES 16384
#define BU1_BASE   32768
#define LDS_BYTES  65536

typedef __attribute__((ext_vector_type(8))) short short8;
typedef __attribute__((ext_vector_type(4))) float f32x4;

__device__ __forceinline__ void gload16(const void* gptr, void* lptr) {
  __builtin_amdgcn_global_load_lds(
      (const __attribute__((address_space(1))) unsigned int*)(unsigned long long)gptr,
      (__attribute__((address_space(3))) unsigned int*)(unsigned int)(unsigned long long)lptr,
      16, 0, 0);
}

// 3-term bf16 split (RNE): f = h + m + l + O(2^-27 |f|)
__device__ __forceinline__ void bsplit(float f, unsigned short& h,
                                       unsigned short& m, unsigned short& l) {
  __hip_bfloat16 bh = __float2bfloat16(f);
  float r1 = f - __bfloat162float(bh);
  __hip_bfloat16 bm = __float2bfloat16(r1);
  __hip_bfloat16 bl = __float2bfloat16(r1 - __bfloat162float(bm));
  h = *reinterpret_cast<unsigned short*>(&bh);
  m = *reinterpret_cast<unsigned short*>(&bm);
  l = *reinterpret_cast<unsigned short*>(&bl);
}

__global__ __launch_bounds__(256)
void ur_hyb(const float* __restrict__ hs,    // [M,1024]
            const float* __restrict__ Wr,    // [64,1024]
            const float* __restrict__ br,    // [64]
            const float* __restrict__ Wu1,   // [256,1024]
            const float* __restrict__ bu1,   // [256]
            const float* __restrict__ Wu2,   // [256]
            const float* __restrict__ bu2,   // [1]
            float* __restrict__ out,         // w[4M] | idx[4M] | k[M]
            int M) {
  __shared__ __align__(16) char smem[LDS_BYTES];

  const int tid = threadIdx.x;
  const int m0 = blockIdx.x * BM;
  // router (fp32 VALU): thread (r, c5) -> tokens 8r..8r+7, cols c5, c5+32
  const int r = tid >> 5, c5 = tid & 31;
  // mfma (u1): wave w -> u1 cols 64w..64w+63
  const int w = tid >> 6, l = tid & 63, g = l >> 4, c = l & 15;

  // ---- staging sources: LDS[row][q] = src[row][q ^ (row&7)] (linear dest) ----
  const int t8 = tid >> 3, k8 = tid & 7;
  const int kx = k8 ^ (t8 & 7);
  const char* pA  = (const char*)hs  + (size_t)(m0 + t8) * 4096 + (kx << 4);
  const char* pBr = (const char*)Wr  + (size_t)t8 * 4096 + (kx << 4);
  const char* pBu = (const char*)Wu1 + (size_t)t8 * 4096 + (kx << 4);
  const unsigned wb = (unsigned)(tid & ~63) * 16u;   // wave-uniform lane-0 part

  // read-offset constants
  const unsigned rsw = (unsigned)(c5 & 7);                     // router Br XOR key
  const unsigned axk0 = (unsigned)(((2 * g) ^ (c & 7)) << 4);  // mfma chunk 2g
  const unsigned axk1 = (unsigned)(((2 * g + 1) ^ (c & 7)) << 4);
  const char* Bub = smem + BU1_BASE + w * 8192 + c * 128;      // u1 rows 64w+16n+c

  float ar[8][2];
#pragma unroll
  for (int j = 0; j < 8; ++j) { ar[j][0] = 0.f; ar[j][1] = 0.f; }
  f32x4 am_[4][4];
#pragma unroll
  for (int s = 0; s < 4; ++s)
#pragma unroll
    for (int n = 0; n < 4; ++n) am_[s][n] = (f32x4){0.f, 0.f, 0.f, 0.f};

  // ---- prologue: stage A/Br(0) into half 0 ----
  gload16(pA, smem + wb);
  gload16(pA + 131072, smem + 4096 + wb);
  gload16(pBr, smem + 8192 + wb);
  gload16(pBr + 131072, smem + 12288 + wb);

  unsigned half = 0;
#pragma unroll 1
  for (int t = 0; t < NT; ++t) {
    // Bu1(t): 8 issues into fixed region (prev readers done at last end-barrier)
#pragma unroll
    for (int li = 0; li < 8; ++li)
      gload16(pBu + (size_t)li * 131072, smem + (BU1_BASE + li * 4096 + wb));
    // A/Br(t+1) into other half (last iter: re-issue same tile, never read)
    const unsigned oh = half ^ HALF_BYTES;
    if (t != NT - 1) { pA += 128; pBr += 128; pBu += 128; }
    gload16(pA, smem + oh + wb);
    gload16(pA + 131072, smem + (oh + 4096 + wb));
    gload16(pBr, smem + (oh + 8192 + wb));
    gload16(pBr + 131072, smem + (oh + 12288 + wb));

    asm volatile("s_waitcnt vmcnt(12)" ::: "memory");  // A/Br(t) resident
    __builtin_amdgcn_s_barrier();
    __builtin_amdgcn_sched_barrier(0);

    // ---- phase 1: router logits, fp32 VALU (overlaps Bu1 + next-ABr flight) ----
    const char* hb = smem + half;
    const char* Ar = hb + r * 1024;
    const char* Brb = hb + 8192 + c5 * 128;
#pragma unroll
    for (int kq = 0; kq < 8; ++kq) {
      f32x4 av[8];
#pragma unroll
      for (int j = 0; j < 8; ++j)
        av[j] = *reinterpret_cast<const f32x4*>(Ar + j * 128 + ((kq ^ j) << 4));
#pragma unroll
      for (int n = 0; n < 2; ++n) {
        const f32x4 bv = *reinterpret_cast<const f32x4*>(
            Brb + n * 4096 + ((kq ^ rsw) << 4));
#pragma unroll
        for (int j = 0; j < 8; ++j) {
          ar[j][n] = fmaf(av[j][0], bv[0], ar[j][n]);
          ar[j][n] = fmaf(av[j][1], bv[1], ar[j][n]);
          ar[j][n] = fmaf(av[j][2], bv[2], ar[j][n]);
          ar[j][n] = fmaf(av[j][3], bv[3], ar[j][n]);
        }
      }
    }

    asm volatile("s_waitcnt vmcnt(4)" ::: "memory");   // Bu1(t) resident
    __builtin_amdgcn_s_barrier();
    __builtin_amdgcn_sched_barrier(0);

    // ---- phase 2: A fragments -> 3-term bf16 split ----
    short8 Ah[4], Am[4], Al[4];
#pragma unroll
    for (int s = 0; s < 4; ++s) {
      const f32x4 v0 = *reinterpret_cast<const f32x4*>(hb + c * 128 + s * 2048 + axk0);
      const f32x4 v1 = *reinterpret_cast<const f32x4*>(hb + c * 128 + s * 2048 + axk1);
#pragma unroll
      for (int e = 0; e < 4; ++e) {
        unsigned short h, m, lo;
        bsplit(v0[e], h, m, lo);
        Ah[s][e] = (short)h; Am[s][e] = (short)m; Al[s][e] = (short)lo;
        bsplit(v1[e], h, m, lo);
        Ah[s][4 + e] = (short)h; Am[s][4 + e] = (short)m; Al[s][4 + e] = (short)lo;
      }
    }

    // ---- phase 3: u1 head via MFMA, 6 products ----
#pragma unroll
    for (int n = 0; n < 4; ++n) {
      const char* bp = Bub + n * 2048;
      const f32x4 u0 = *reinterpret_cast<const f32x4*>(bp + axk0);
      const f32x4 u1v = *reinterpret_cast<const f32x4*>(bp + axk1);
      short8 Bh, Bm, Bl;
#pragma unroll
      for (int e = 0; e < 4; ++e) {
        unsigned short h, m, lo;
        bsplit(u0[e], h, m, lo);
        Bh[e] = (short)h; Bm[e] = (short)m; Bl[e] = (short)lo;
        bsplit(u1v[e], h, m, lo);
        Bh[4 + e] = (short)h; Bm[4 + e] = (short)m; Bl[4 + e] = (short)lo;
      }
#pragma unroll
      for (int s = 0; s < 4; ++s) {
        am_[s][n] = __builtin_amdgcn_mfma_f32_16x16x32_bf16(Al[s], Bh, am_[s][n], 0, 0, 0);
        am_[s][n] = __builtin_amdgcn_mfma_f32_16x16x32_bf16(Ah[s], Bl, am_[s][n], 0, 0, 0);
        am_[s][n] = __builtin_amdgcn_mfma_f32_16x16x32_bf16(Am[s], Bm, am_[s][n], 0, 0, 0);
        am_[s][n] = __builtin_amdgcn_mfma_f32_16x16x32_bf16(Am[s], Bh, am_[s][n], 0, 0, 0);
        am_[s][n] = __builtin_amdgcn_mfma_f32_16x16x32_bf16(Ah[s], Bm, am_[s][n], 0, 0, 0);
        am_[s][n] = __builtin_amdgcn_mfma_f32_16x16x32_bf16(Ah[s], Bh, am_[s][n], 0, 0, 0);
      }
    }

    __builtin_amdgcn_s_barrier();   // all readers of Bu1/half done
    half = oh;
  }
  __syncthreads();     // drains vmcnt(0) incl. dangling ABr(32); overlay safe

  // ---- epilogue (identical to R11) ----
  float* Lg = reinterpret_cast<float*>(smem);                 // [64][65]
  float* Xp = reinterpret_cast<float*>(smem + 16640);         // [64][65]
  float* Xs = reinterpret_cast<float*>(smem + 33280);         // [64]

#pragma unroll
  for (int n = 0; n < 2; ++n) {
    const int col = c5 + 32 * n;
    const float bias = br[col];
#pragma unroll
    for (int j = 0; j < 8; ++j) Lg[(8 * r + j) * 65 + col] = ar[j][n] + bias;
  }

  float xp[4][4];
#pragma unroll
  for (int s = 0; s < 4; ++s)
#pragma unroll
    for (int reg = 0; reg < 4; ++reg) xp[s][reg] = 0.f;
#pragma unroll
  for (int n = 0; n < 4; ++n) {
    const int qd = 64 * w + 16 * n + c;
    const float w2 = Wu2[qd];
    const float b1 = bu1[qd];
#pragma unroll
    for (int s = 0; s < 4; ++s)
#pragma unroll
      for (int reg = 0; reg < 4; ++reg) {
        float h = am_[s][n][reg] + b1;
        float ge = 0.5f * h * (1.f + erff(h * 0.70710678118654752440f));
        xp[s][reg] = fmaf(ge, w2, xp[s][reg]);
      }
  }
#pragma unroll
  for (int s = 0; s < 4; ++s)
#pragma unroll
    for (int reg = 0; reg < 4; ++reg)
      Xp[(w * 16 + c) * 65 + 16 * s + 4 * g + reg] = xp[s][reg];
  __syncthreads();

  if (tid < BM) {
    float x = bu2[0];
#pragma unroll
    for (int cc = 0; cc < 64; ++cc) x += Xp[cc * 65 + tid];
    Xs[tid] = x;
  }
  __syncthreads();

  const size_t Moff_i = 4 * (size_t)M;
  const size_t Moff_k = 8 * (size_t)M;

  for (int t = w; t < BM; t += 4) {
    float cur = Lg[t * 65 + l];
    float topv[4];
    int topi[4];
#pragma unroll
    for (int s = 0; s < 4; ++s) {
      float mv = cur;
      int mi = l;
#pragma unroll
      for (int off = 32; off >= 1; off >>= 1) {
        float ov = __shfl_xor(mv, off, 64);
        int oi = __shfl_xor(mi, off, 64);
        if (ov > mv || (ov == mv && oi < mi)) { mv = ov; mi = oi; }
      }
      topv[s] = mv;
      topi[s] = mi;
      if (l == mi) cur = -INFINITY;        // stable: lowest index wins ties
    }
    if (l == 0) {
      const int token = m0 + t;
      float x = Xs[t];
      float u = 1.f / (1.f + expf(-x));
      float kf = fmaf(3.f, u, 1.f);
      int kv = (int)rintf(kf);             // round-half-even == jnp.round
      kv = kv < 1 ? 1 : (kv > 4 ? 4 : kv);

      float wv[4];
#pragma unroll
      for (int s = 0; s < 4; ++s) wv[s] = (s < kv) ? topv[s] : 0.f;
      float mx = fmaxf(fmaxf(wv[0], wv[1]), fmaxf(wv[2], wv[3]));
      float e[4], sum = 0.f;
#pragma unroll
      for (int s = 0; s < 4; ++s) { e[s] = expf(wv[s] - mx); sum += e[s]; }
      float inv = 1.f / sum;
#pragma unroll
      for (int s = 0; s < 4; ++s) {
        out[(size_t)token * 4 + s] = e[s] * inv;
        out[Moff_i + (size_t)token * 4 + s] = (s < kv) ? (float)topi[s] : -1.0f;
      }
      out[Moff_k + token] = (float)kv;
    }
  }
}

extern "C" void kernel_launch(void* const* d_in, const int* in_sizes, int n_in,
                              void* d_out, int out_size, void* d_ws, size_t ws_size,
                              hipStream_t stream) {
  (void)n_in; (void)d_ws; (void)ws_size; (void)out_size;
  const float* hs  = (const float*)d_in[0];
  const float* Wr  = (const float*)d_in[1];
  const float* br  = (const float*)d_in[2];
  const float* Wu1 = (const float*)d_in[3];
  const float* bu1 = (const float*)d_in[4];
  const float* Wu2 = (const float*)d_in[5];
  const float* bu2 = (const float*)d_in[6];
  float* out = (float*)d_out;

  const int M = in_sizes[0] / DIM;  // 32768
  dim3 grid(M / BM);                // 512 blocks, 64 KB LDS, 2 blocks/CU
  dim3 block(256);
  hipLaunchKernelGGL(ur_hyb, grid, block, 0, stream,
                     hs, Wr, br, Wu1, bu1, Wu2, bu2, out, M);
}

// Round 13
// 279.882 us; speedup vs baseline: 1.5498x; 1.0524x over previous
//
#include <hip/hip_runtime.h>
#include <hip/hip_bf16.h>
#include <math.h>

#define DIM 1024
#define NE  64
#define BM  64
#define NT  32                    // 1024/32 k-tiles
// LDS: [2][A 8KB | Br 8KB] dbuf + Bu1 32KB single = 64KB
#define HALF_BYTES 16384
#define BU1_BASE   32768
#define LDS_BYTES  65536

typedef __attribute__((ext_vector_type(8))) short short8;
typedef __attribute__((ext_vector_type(4))) float f32x4;

__device__ __forceinline__ void gload16(const void* gptr, void* lptr) {
  __builtin_amdgcn_global_load_lds(
      (const __attribute__((address_space(1))) unsigned int*)(unsigned long long)gptr,
      (__attribute__((address_space(3))) unsigned int*)(unsigned int)(unsigned long long)lptr,
      16, 0, 0);
}

// 3-term bf16 split (RNE): f = h + m + l + O(2^-27 |f|)
__device__ __forceinline__ void bsplit(float f, unsigned short& h,
                                       unsigned short& m, unsigned short& l) {
  __hip_bfloat16 bh = __float2bfloat16(f);
  float r1 = f - __bfloat162float(bh);
  __hip_bfloat16 bm = __float2bfloat16(r1);
  __hip_bfloat16 bl = __float2bfloat16(r1 - __bfloat162float(bm));
  h = *reinterpret_cast<unsigned short*>(&bh);
  m = *reinterpret_cast<unsigned short*>(&bm);
  l = *reinterpret_cast<unsigned short*>(&bl);
}

__global__ __launch_bounds__(512)
void ur_hyb(const float* __restrict__ hs,    // [M,1024]
            const float* __restrict__ Wr,    // [64,1024]
            const float* __restrict__ br,    // [64]
            const float* __restrict__ Wu1,   // [256,1024]
            const float* __restrict__ bu1,   // [256]
            const float* __restrict__ Wu2,   // [256]
            const float* __restrict__ bu2,   // [1]
            float* __restrict__ out,         // w[4M] | idx[4M] | k[M]
            int M) {
  __shared__ __align__(16) char smem[LDS_BYTES];

  const int tid = threadIdx.x;
  const int m0 = blockIdx.x * BM;
  const int w2 = tid >> 6, l = tid & 63;     // wave, lane
  const int g = l >> 4, c = l & 15;          // mfma fragment coords
  const int rcol = 8 * w2 + (l & 7);         // router col (disjoint per wave)
  const int jb = l >> 3;                     // router token base

  // ---- staging sources: LDS[row][q] = src[row][q ^ (row&7)] (linear dest) ----
  const int t8 = tid >> 3, k8 = tid & 7;
  const int kx = k8 ^ (t8 & 7);
  const char* pA  = (const char*)hs  + (size_t)(m0 + t8) * 4096 + (kx << 4);
  const char* pBr = (const char*)Wr  + (size_t)t8 * 4096 + (kx << 4);
  const char* pBu = (const char*)Wu1 + (size_t)t8 * 4096 + (kx << 4);
  const unsigned wb = (unsigned)(tid & ~63) * 16u;   // wave-uniform lane-0 part

  // fragment read offsets (R11-verified scheme; row&7 == c&7)
  const unsigned axk0 = (unsigned)(((2 * g) ^ (c & 7)) << 4);
  const unsigned axk1 = (unsigned)(((2 * g + 1) ^ (c & 7)) << 4);

  float ar[8];
#pragma unroll
  for (int j = 0; j < 8; ++j) ar[j] = 0.f;
  f32x4 am_[4][2];
#pragma unroll
  for (int s = 0; s < 4; ++s)
#pragma unroll
    for (int n = 0; n < 2; ++n) am_[s][n] = (f32x4){0.f, 0.f, 0.f, 0.f};

  // ---- prologue: stage A/Br(0) into half 0 (1 issue each at 512 thr) ----
  gload16(pA, smem + wb);
  gload16(pBr, smem + 8192 + wb);

  unsigned half = 0;
#pragma unroll 1
  for (int t = 0; t < NT; ++t) {
    // Bu1(t): 4 issues (prev readers done at last end-barrier)
#pragma unroll
    for (int li = 0; li < 4; ++li)
      gload16(pBu + (size_t)li * 262144, smem + (BU1_BASE + li * 8192 + wb));
    const unsigned oh = half ^ HALF_BYTES;
    if (t != NT - 1) { pA += 128; pBr += 128; pBu += 128; }
    gload16(pA, smem + oh + wb);
    gload16(pBr, smem + (oh + 8192 + wb));

    asm volatile("s_waitcnt vmcnt(6)" ::: "memory");  // A/Br(t) resident
    __builtin_amdgcn_s_barrier();
    __builtin_amdgcn_sched_barrier(0);

    // ---- phase 1: router, fp32 VALU. A rows jb+8j, B col rcol ----
    const char* hb = smem + half;
#pragma unroll
    for (int kq = 0; kq < 8; ++kq) {
      const char* ab = hb + jb * 128 + (((unsigned)(kq ^ jb)) << 4);
      const f32x4 bv = *reinterpret_cast<const f32x4*>(
          hb + 8192 + rcol * 128 + (((unsigned)(kq ^ (l & 7))) << 4));
#pragma unroll
      for (int j = 0; j < 8; ++j) {
        const f32x4 av = *reinterpret_cast<const f32x4*>(ab + j * 1024);
        ar[j] = fmaf(av[0], bv[0], ar[j]);
        ar[j] = fmaf(av[1], bv[1], ar[j]);
        ar[j] = fmaf(av[2], bv[2], ar[j]);
        ar[j] = fmaf(av[3], bv[3], ar[j]);
      }
    }

    asm volatile("s_waitcnt vmcnt(2)" ::: "memory");   // Bu1(t) resident
    __builtin_amdgcn_s_barrier();
    __builtin_amdgcn_sched_barrier(0);

    // ---- phase 2: B splits first (lower peak pressure), then per-s A+MFMA ----
    short8 Bh[2], Bm[2], Bl[2];
#pragma unroll
    for (int n = 0; n < 2; ++n) {
      const char* bp = smem + BU1_BASE + w2 * 4096 + n * 2048 + c * 128;
      const f32x4 u0 = *reinterpret_cast<const f32x4*>(bp + axk0);
      const f32x4 u1v = *reinterpret_cast<const f32x4*>(bp + axk1);
#pragma unroll
      for (int e = 0; e < 4; ++e) {
        unsigned short h, m, lo;
        bsplit(u0[e], h, m, lo);
        Bh[n][e] = (short)h; Bm[n][e] = (short)m; Bl[n][e] = (short)lo;
        bsplit(u1v[e], h, m, lo);
        Bh[n][4 + e] = (short)h; Bm[n][4 + e] = (short)m; Bl[n][4 + e] = (short)lo;
      }
    }
#pragma unroll
    for (int s = 0; s < 4; ++s) {
      const f32x4 v0 = *reinterpret_cast<const f32x4*>(hb + c * 128 + s * 2048 + axk0);
      const f32x4 v1 = *reinterpret_cast<const f32x4*>(hb + c * 128 + s * 2048 + axk1);
      short8 Ah, Am, Al;
#pragma unroll
      for (int e = 0; e < 4; ++e) {
        unsigned short h, m, lo;
        bsplit(v0[e], h, m, lo);
        Ah[e] = (short)h; Am[e] = (short)m; Al[e] = (short)lo;
        bsplit(v1[e], h, m, lo);
        Ah[4 + e] = (short)h; Am[4 + e] = (short)m; Al[4 + e] = (short)lo;
      }
#pragma unroll
      for (int n = 0; n < 2; ++n) {
        am_[s][n] = __builtin_amdgcn_mfma_f32_16x16x32_bf16(Al, Bh[n], am_[s][n], 0, 0, 0);
        am_[s][n] = __builtin_amdgcn_mfma_f32_16x16x32_bf16(Ah, Bl[n], am_[s][n], 0, 0, 0);
        am_[s][n] = __builtin_amdgcn_mfma_f32_16x16x32_bf16(Am, Bm[n], am_[s][n], 0, 0, 0);
        am_[s][n] = __builtin_amdgcn_mfma_f32_16x16x32_bf16(Am, Bh[n], am_[s][n], 0, 0, 0);
        am_[s][n] = __builtin_amdgcn_mfma_f32_16x16x32_bf16(Ah, Bm[n], am_[s][n], 0, 0, 0);
        am_[s][n] = __builtin_amdgcn_mfma_f32_16x16x32_bf16(Ah, Bh[n], am_[s][n], 0, 0, 0);
      }
    }

    __builtin_amdgcn_s_barrier();   // all readers of Bu1/half done
    half = oh;
  }
  __syncthreads();     // drains dangling loads; overlay safe

  // ---- epilogue ----
  float* Lg = reinterpret_cast<float*>(smem);                 // [64][65]
  float* Xp = reinterpret_cast<float*>(smem + 16640);         // [128][65]
  float* Xs = reinterpret_cast<float*>(smem + 49920);         // [64]

  {
    const float bias = br[rcol];
#pragma unroll
    for (int j = 0; j < 8; ++j) Lg[(jb + 8 * j) * 65 + rcol] = ar[j] + bias;
  }

  // u1 -> GELU -> dot W_u2. C/D [m89, R11-verified]:
  // am_[s][n][reg] = h1[16s+4g+reg][32w2+16n+c]
  float xp[4][4];
#pragma unroll
  for (int s = 0; s < 4; ++s)
#pragma unroll
    for (int reg = 0; reg < 4; ++reg) xp[s][reg] = 0.f;
#pragma unroll
  for (int n = 0; n < 2; ++n) {
    const int qd = 32 * w2 + 16 * n + c;
    const float w2f = Wu2[qd];
    const float b1 = bu1[qd];
#pragma unroll
    for (int s = 0; s < 4; ++s)
#pragma unroll
      for (int reg = 0; reg < 4; ++reg) {
        float h = am_[s][n][reg] + b1;
        float ge = 0.5f * h * (1.f + erff(h * 0.70710678118654752440f));
        xp[s][reg] = fmaf(ge, w2f, xp[s][reg]);
      }
  }
#pragma unroll
  for (int s = 0; s < 4; ++s)
#pragma unroll
    for (int reg = 0; reg < 4; ++reg)
      Xp[(w2 * 16 + c) * 65 + 16 * s + 4 * g + reg] = xp[s][reg];
  __syncthreads();

  if (tid < BM) {
    float x = bu2[0];
#pragma unroll
    for (int cc = 0; cc < 128; ++cc) x += Xp[cc * 65 + tid];
    Xs[tid] = x;
  }
  __syncthreads();

  // ---- per-token top-4 + masked softmax: one wave per token ----
  const size_t Moff_i = 4 * (size_t)M;
  const size_t Moff_k = 8 * (size_t)M;

  for (int t = w2; t < BM; t += 8) {
    float cur = Lg[t * 65 + l];
    float topv[4];
    int topi[4];
#pragma unroll
    for (int s = 0; s < 4; ++s) {
      float mv = cur;
      int mi = l;
#pragma unroll
      for (int off = 32; off >= 1; off >>= 1) {
        float ov = __shfl_xor(mv, off, 64);
        int oi = __shfl_xor(mi, off, 64);
        if (ov > mv || (ov == mv && oi < mi)) { mv = ov; mi = oi; }
      }
      topv[s] = mv;
      topi[s] = mi;
      if (l == mi) cur = -INFINITY;        // stable: lowest index wins ties
    }
    if (l == 0) {
      const int token = m0 + t;
      float x = Xs[t];
      float u = 1.f / (1.f + expf(-x));
      float kf = fmaf(3.f, u, 1.f);
      int kv = (int)rintf(kf);             // round-half-even == jnp.round
      kv = kv < 1 ? 1 : (kv > 4 ? 4 : kv);

      float wv[4];
#pragma unroll
      for (int s = 0; s < 4; ++s) wv[s] = (s < kv) ? topv[s] : 0.f;
      float mx = fmaxf(fmaxf(wv[0], wv[1]), fmaxf(wv[2], wv[3]));
      float e[4], sum = 0.f;
#pragma unroll
      for (int s = 0; s < 4; ++s) { e[s] = expf(wv[s] - mx); sum += e[s]; }
      float inv = 1.f / sum;
#pragma unroll
      for (int s = 0; s < 4; ++s) {
        out[(size_t)token * 4 + s] = e[s] * inv;
        out[Moff_i + (size_t)token * 4 + s] = (s < kv) ? (float)topi[s] : -1.0f;
      }
      out[Moff_k + token] = (float)kv;
    }
  }
}

extern "C" void kernel_launch(void* const* d_in, const int* in_sizes, int n_in,
                              void* d_out, int out_size, void* d_ws, size_t ws_size,
                              hipStream_t stream) {
  (void)n_in; (void)d_ws; (void)ws_size; (void)out_size;
  const float* hs  = (const float*)d_in[0];
  const float* Wr  = (const float*)d_in[1];
  const float* br  = (const float*)d_in[2];
  const float* Wu1 = (const float*)d_in[3];
  const float* bu1 = (const float*)d_in[4];
  const float* Wu2 = (const float*)d_in[5];
  const float* bu2 = (const float*)d_in[6];
  float* out = (float*)d_out;

  const int M = in_sizes[0] / DIM;  // 32768
  dim3 grid(M / BM);                // 512 blocks, 64 KB LDS, 2 blocks/CU
  dim3 block(512);                  // 8 waves -> 4 waves/SIMD
  hipLaunchKernelGGL(ur_hyb, grid, block, 0, stream,
                     hs, Wr, br, Wu1, bu1, Wu2, bu2, out, M);
}